// Round 3
// baseline (271.221 us; speedup 1.0000x reference)
//
#include <hip/hip_runtime.h>

// SharedAdditiveKAN: y = spline(x) @ mix^T + bias
// x: [65536, 512] fp32; bases/slopes: [512, 16] fp32; mix: [512, 512] fp32; bias: [512]
//
// R5: OCCUPANCY fix. R2/R4 post-mortem: acc[4][8]=128 AGPR + ~112 VGPR = ~240
// unified regs/wave -> 2 waves/SIMD -> exactly ONE 8-wave block per CU. Every
// __syncthreads drain (vmcnt(0) incl. just-issued prefetches) idled the whole
// CU; per-kt issue work ~500cy vs ~7800cy measured -> pure latency exposure.
// Barrier-count restructure (R4) changed nothing because there was no second
// block to cover the stalls.
// Fix: wave tile 32x128 -> acc[2][8]=64 regs, __launch_bounds__(512,4) caps
// 128 unified regs/wave -> 4 waves/SIMD; LDS trimmed to 81920 B (unpadded
// XOR-permuted spline table) -> 2 blocks/CU = 16 waves/CU. Cross-block overlap
// now hides barrier drains. Cost: BN=256 => spline VALU 2x chip-wide, x read
// 2x (L2-hit via XCD swizzle keeping n-pairs co-resident).
//
// GEMM: BM=128 x BN=256, BK=32, 512 thr = 8 waves (4m x 2n), wave 32x128,
// mfma_f32_16x16x32_bf16, 2x8 frags/wave.

#define DIMK 512
#define DIMN 512

typedef unsigned short u16;
typedef unsigned int u32;
typedef __attribute__((ext_vector_type(8))) __bf16 bf16x8;
typedef __attribute__((ext_vector_type(4))) float f32x4;

__device__ __forceinline__ u32 bf16rne(float f) {
    u32 u = __float_as_uint(f);
    return (u + 0x7fffu + ((u >> 16) & 1u)) >> 16;  // round-to-nearest-even
}

// Prep: convert mix fp32 -> bf16 (ushort bits) into ws, row-major.
__global__ void prep_kernel(const float* __restrict__ mix,
                            u16* __restrict__ mixb) {
    int t = blockIdx.x * 256 + threadIdx.x;             // 65536 threads
    float4 v = reinterpret_cast<const float4*>(mix)[t]; // 4 mix elems each
    ushort4 o;
    o.x = (u16)bf16rne(v.x);
    o.y = (u16)bf16rne(v.y);
    o.z = (u16)bf16rne(v.z);
    o.w = (u16)bf16rne(v.w);
    reinterpret_cast<ushort4*>(mixb)[t] = o;
}

// Spline-table word index: dim*16 + (g ^ perm(dim)). The 2-bit perm from dim
// bits 3..4 spreads the 4 akg-groups of a wave across different bank offsets
// (unpadded table: all lanes share dim parity => 16-bank confinement; the
// XOR keeps collisions ~4-way avg instead of clustered). Bijective per dim.
__device__ __forceinline__ int tab_word(int dim, int g) {
    return dim * 16 + (g ^ (((dim >> 3) & 3) << 2));
}

__global__ __launch_bounds__(512, 4) void kan_kernel(
    const float* __restrict__ x, const float* __restrict__ bases,
    const float* __restrict__ slopes, const u16* __restrict__ mixb,
    const float* __restrict__ bias, float* __restrict__ y) {
    // Spline table: (base,slope) packed bf16 pair, unpadded 512x16 u32.
    __shared__ u32 s_tab[DIMK * 16];                 // 32768 B
    // Double-buffered XOR-swizzled tiles: row r, k-chunk c (16B) at
    // chunk (r<<2)|(c^((r>>1)&3)).
    __shared__ __align__(16) u16 sA[2][128 * 32];    // 16384 B
    __shared__ __align__(16) u16 sB[2][256 * 32];    // 32768 B
    // total 81920 B exactly -> 2 blocks/CU (160 KiB)

    const int tid = threadIdx.x;
    const int lane = tid & 63;
    const int wid = tid >> 6;       // 0..7
    const int quad = lane >> 4;     // 0..3
    const int l15 = lane & 15;
    const int wave_m = wid >> 1;    // 0..3 : 32-row slice
    const int wave_n = wid & 1;     // 0..1 : 128-col half
    // XCD-chunked swizzle (1024 blocks % 8 == 0 -> bijective): the two
    // n-halves of an m-tile (swz pair 2k,2k+1) land on the same XCD.
    const int swz = (blockIdx.x & 7) * 128 + (blockIdx.x >> 3);
    const int m0 = (swz >> 1) * 128;
    const int n0 = (swz & 1) * 256;

    // ---- one-time: load spline table into LDS (coalesced fp32 reads) ----
#pragma unroll
    for (int k = 0; k < 16; k++) {
        int i = tid + k * 512;      // 0..8191 over [D=512][G=16]
        u32 p = bf16rne(bases[i]) | (bf16rne(slopes[i]) << 16);
        s_tab[tab_word(i >> 4, i & 15)] = p;
    }

    // A staging: thread t handles row ar (0..127), k-chunk akg (0..3) = 8 elems
    const int ar = tid >> 2;
    const int akg = tid & 3;
    const int awchunk = (ar << 2) | (akg ^ ((ar >> 1) & 3));
    const float4* xrow =
        reinterpret_cast<const float4*>(x + (size_t)(m0 + ar) * DIMK) + akg * 2;

    f32x4 acc[2][8];
#pragma unroll
    for (int i = 0; i < 2; i++)
#pragma unroll
        for (int j = 0; j < 8; j++) acc[i][j] = (f32x4){0.f, 0.f, 0.f, 0.f};

    // ---- staging helpers ----
    auto stage_a = [&](u16* sAb, float4 a, float4 b, int kt) {
        float xs[8] = {a.x, a.y, a.z, a.w, b.x, b.y, b.z, b.w};
        const int dbase = kt * 32 + akg * 8;
        u32 h[8];
#pragma unroll
        for (int j = 0; j < 8; j++) {
            // EXACT replication of reference index math (fp32).
            float xn = fminf(fmaxf((xs[j] + 1.0f) * 0.5f, 0.0f), 0.999999f);
            float tt = xn * 16.0f;
            int idx = (int)tt;  // 0..15 guaranteed
            u32 p = s_tab[tab_word(dbase + j, idx)];
            float base = __uint_as_float(p << 16);
            float slope = __uint_as_float(p & 0xffff0000u);
            float sp = fmaf(slope, tt - (float)idx, base);
            h[j] = bf16rne(sp);
        }
        int4 pk = make_int4((int)(h[0] | (h[1] << 16)), (int)(h[2] | (h[3] << 16)),
                            (int)(h[4] | (h[5] << 16)), (int)(h[6] | (h[7] << 16)));
        *reinterpret_cast<int4*>(&sAb[awchunk * 8]) = pk;
    };
    auto stage_b = [&](u16* sBb, int kt) {
#pragma unroll
        for (int i = 0; i < 2; i++) {
            int grp = wid * 2 + i;                // 16-row group, 0..15
            int n = grp * 16 + (lane >> 2);       // local B row 0..255
            int c = (lane & 3) ^ ((n >> 1) & 3);  // global k-chunk this lane fetches
            const u16* gsrc = mixb + (size_t)(n0 + n) * DIMK + kt * 32 + c * 8;
            __builtin_amdgcn_global_load_lds(
                (const __attribute__((address_space(1))) void*)gsrc,
                (__attribute__((address_space(3))) void*)(&sBb[grp * 512]),
                16, 0, 0);
        }
    };

    // ---- prologue ----
    float4 p0 = xrow[0], p1 = xrow[1];           // x(kt=0)
    __syncthreads();                             // s_tab ready
    stage_a(&sA[0][0], p0, p1, 0);
    stage_b(&sB[0][0], 0);
    float4 xs0a = xrow[8], xs0b = xrow[9];       // x(kt=1)
    __syncthreads();                             // buf0 staged

    for (int kt = 0; kt < 16; ++kt) {
        const int p = kt & 1;
        const int q = p ^ 1;

        // issue next-buffer B loads first (longest path to the barrier)
        if (kt < 15) stage_b(&sB[q][0], kt + 1);

        // x prefetch for kt+2
        float4 xna = xs0a, xnb = xs0b;
        if (kt < 14) {
            xna = xrow[(kt + 2) * 8];
            xnb = xrow[(kt + 2) * 8 + 1];
        }

        // spline + ds_write A for kt+1, overlapping compute below
        if (kt < 15) stage_a(&sA[q][0], xs0a, xs0b, kt + 1);

        // ---- compute on buf p: 16 MFMAs per wave ----
        const u16* sAc = &sA[p][0];
        const u16* sBc = &sB[p][0];
        bf16x8 afrag[2];
#pragma unroll
        for (int fm = 0; fm < 2; fm++) {
            int m_l = wave_m * 32 + fm * 16 + l15;
            int ci = (m_l << 2) | (quad ^ ((m_l >> 1) & 3));
            afrag[fm] = *reinterpret_cast<const bf16x8*>(&sAc[ci * 8]);
        }
#pragma unroll
        for (int fn = 0; fn < 8; fn++) {
            int n_l = wave_n * 128 + fn * 16 + l15;
            int ci = (n_l << 2) | (quad ^ ((n_l >> 1) & 3));
            bf16x8 bfrag = *reinterpret_cast<const bf16x8*>(&sBc[ci * 8]);
#pragma unroll
            for (int fm = 0; fm < 2; fm++)
                acc[fm][fn] = __builtin_amdgcn_mfma_f32_16x16x32_bf16(
                    afrag[fm], bfrag, acc[fm][fn], 0, 0, 0);
        }

        if (kt < 15) __syncthreads();  // next buffer staged & visible
        xs0a = xna; xs0b = xnb;
    }

    // ---- epilogue: C/D layout col=lane&15, row=quad*4+j ----
#pragma unroll
    for (int fn = 0; fn < 8; fn++) {
        int o = n0 + wave_n * 128 + fn * 16 + l15;
        float bv = bias[o];
#pragma unroll
        for (int fm = 0; fm < 2; fm++) {
            int row = m0 + wave_m * 32 + fm * 16 + quad * 4;
            float* yp = y + (size_t)row * DIMN + o;
#pragma unroll
            for (int j = 0; j < 4; j++)
                yp[(size_t)j * DIMN] = acc[fm][fn][j] + bv;
        }
    }
}

extern "C" void kernel_launch(void* const* d_in, const int* in_sizes, int n_in,
                              void* d_out, int out_size, void* d_ws, size_t ws_size,
                              hipStream_t stream) {
    const float* x = (const float*)d_in[0];
    const float* bases = (const float*)d_in[1];
    const float* slopes = (const float*)d_in[2];
    const float* mix = (const float*)d_in[3];
    const float* bias = (const float*)d_in[4];
    float* y = (float*)d_out;

    u16* mixb = (u16*)d_ws;  // 512 KB bf16 mix

    hipLaunchKernelGGL(prep_kernel, dim3(256), dim3(256), 0, stream, mix, mixb);
    hipLaunchKernelGGL(kan_kernel, dim3(1024), dim3(512), 0, stream,
                       x, bases, slopes, mixb, bias, y);
}

// Round 5
// 266.916 us; speedup vs baseline: 1.0161x; 1.0161x over previous
//
#include <hip/hip_runtime.h>

// SharedAdditiveKAN: y = spline(x) @ mix^T + bias
// x: [65536, 512] fp32; bases/slopes: [512, 16] fp32; mix: [512, 512] fp32; bias: [512]
//
// R7 = R6 resubmitted verbatim (R6 bench died to container infra, no signal).
// R6: counted-vmcnt barriers + conflict-free spline table. R5 post-mortem:
// (1) per-kt __syncthreads (vmcnt(0) drain) re-synced all waves every kt ->
// VALU/MFMA/LDS pipes ran sequentially (util sum ~86%) and the drain killed
// the freshly-issued x HBM prefetch each iteration; 2 blocks/CU couldn't
// cover it. Fix = T4: issue exactly {2 glds B, 2 x loads} per kt in pinned
// order; end with s_waitcnt vmcnt(2) lgkmcnt(0) + raw s_barrier -> glds
// (oldest) guaranteed done, x prefetch stays in flight ACROSS the barrier.
// (2) R5's unpadded XOR table quadrupled bank conflicts (1.18M->4.57M): the
// 4 akg dims (d, d+8..) share a bank-half at stride-16. Fix: transposed-XOR
// table word = idx*512 + (dim^idx) -> bank = (dim%32)^idx: distinct idx =
// distinct banks, equal idx = broadcast; 32 KB, no padding, LDS stays
// exactly 81920 B = 2 blocks/CU.
//
// GEMM: BM=128 x BN=256, BK=32, 512 thr = 8 waves (4m x 2n), wave 32x128,
// mfma_f32_16x16x32_bf16, 2x8 frags/wave, acc[2][8] (geometry == R5).

#define DIMK 512
#define DIMN 512

typedef unsigned short u16;
typedef unsigned int u32;
typedef __attribute__((ext_vector_type(8))) __bf16 bf16x8;
typedef __attribute__((ext_vector_type(4))) float f32x4;

__device__ __forceinline__ u32 bf16rne(float f) {
    u32 u = __float_as_uint(f);
    return (u + 0x7fffu + ((u >> 16) & 1u)) >> 16;  // round-to-nearest-even
}

// Prep: convert mix fp32 -> bf16 (ushort bits) into ws, row-major.
__global__ void prep_kernel(const float* __restrict__ mix,
                            u16* __restrict__ mixb) {
    int t = blockIdx.x * 256 + threadIdx.x;             // 65536 threads
    float4 v = reinterpret_cast<const float4*>(mix)[t]; // 4 mix elems each
    ushort4 o;
    o.x = (u16)bf16rne(v.x);
    o.y = (u16)bf16rne(v.y);
    o.z = (u16)bf16rne(v.z);
    o.w = (u16)bf16rne(v.w);
    reinterpret_cast<ushort4*>(mixb)[t] = o;
}

__global__ __launch_bounds__(512, 4) void kan_kernel(
    const float* __restrict__ x, const float* __restrict__ bases,
    const float* __restrict__ slopes, const u16* __restrict__ mixb,
    const float* __restrict__ bias, float* __restrict__ y) {
    // Transposed-XOR spline table: word = idx*512 + (dim ^ idx).
    // bank = (dim%32)^idx -> conflict-free gathers (distinct idx -> distinct
    // banks; equal idx -> broadcast). No padding needed.
    __shared__ u32 s_tab[16 * DIMK];                 // 32768 B
    // Double-buffered XOR-swizzled tiles: row r, k-chunk c (16B) at
    // chunk (r<<2)|(c^((r>>1)&3)).
    __shared__ __align__(16) u16 sA[2][128 * 32];    // 16384 B
    __shared__ __align__(16) u16 sB[2][256 * 32];    // 32768 B
    // total 81920 B exactly -> 2 blocks/CU (160 KiB)

    const int tid = threadIdx.x;
    const int lane = tid & 63;
    const int wid = tid >> 6;       // 0..7
    const int quad = lane >> 4;     // 0..3
    const int l15 = lane & 15;
    const int wave_m = wid >> 1;    // 0..3 : 32-row slice
    const int wave_n = wid & 1;     // 0..1 : 128-col half
    // XCD-chunked swizzle (1024 % 8 == 0 -> bijective): the two n-halves of
    // an m-tile land on the same XCD for x L2 reuse.
    const int swz = (blockIdx.x & 7) * 128 + (blockIdx.x >> 3);
    const int m0 = (swz >> 1) * 128;
    const int n0 = (swz & 1) * 256;

    // ---- one-time: load spline table into LDS (coalesced fp32 reads) ----
#pragma unroll
    for (int k = 0; k < 16; k++) {
        int i = tid + k * 512;      // 0..8191 over [D=512][G=16]
        int dim = i >> 4, g = i & 15;
        u32 p = bf16rne(bases[i]) | (bf16rne(slopes[i]) << 16);
        s_tab[g * DIMK + (dim ^ g)] = p;
    }

    // A staging: thread t handles row ar (0..127), k-chunk akg (0..3) = 8 elems
    const int ar = tid >> 2;
    const int akg = tid & 3;
    const int awchunk = (ar << 2) | (akg ^ ((ar >> 1) & 3));
    const float4* xrow =
        reinterpret_cast<const float4*>(x + (size_t)(m0 + ar) * DIMK) + akg * 2;

    f32x4 acc[2][8];
#pragma unroll
    for (int i = 0; i < 2; i++)
#pragma unroll
        for (int j = 0; j < 8; j++) acc[i][j] = (f32x4){0.f, 0.f, 0.f, 0.f};

    // ---- staging helpers ----
    auto stage_a = [&](u16* sAb, float4 a, float4 b, int kt) {
        float xs[8] = {a.x, a.y, a.z, a.w, b.x, b.y, b.z, b.w};
        const int dbase = kt * 32 + akg * 8;
        u32 h[8];
#pragma unroll
        for (int j = 0; j < 8; j++) {
            // EXACT replication of reference index math (fp32).
            float xn = fminf(fmaxf((xs[j] + 1.0f) * 0.5f, 0.0f), 0.999999f);
            float tt = xn * 16.0f;
            int idx = (int)tt;  // 0..15 guaranteed
            u32 p = s_tab[idx * DIMK + ((dbase + j) ^ idx)];
            float base = __uint_as_float(p << 16);
            float slope = __uint_as_float(p & 0xffff0000u);
            float sp = fmaf(slope, tt - (float)idx, base);
            h[j] = bf16rne(sp);
        }
        int4 pk = make_int4((int)(h[0] | (h[1] << 16)), (int)(h[2] | (h[3] << 16)),
                            (int)(h[4] | (h[5] << 16)), (int)(h[6] | (h[7] << 16)));
        *reinterpret_cast<int4*>(&sAb[awchunk * 8]) = pk;
    };
    auto stage_b = [&](u16* sBb, int kt) {
#pragma unroll
        for (int i = 0; i < 2; i++) {
            int grp = wid * 2 + i;                // 16-row group, 0..15
            int n = grp * 16 + (lane >> 2);       // local B row 0..255
            int c = (lane & 3) ^ ((n >> 1) & 3);  // global k-chunk this lane fetches
            const u16* gsrc = mixb + (size_t)(n0 + n) * DIMK + kt * 32 + c * 8;
            __builtin_amdgcn_global_load_lds(
                (const __attribute__((address_space(1))) void*)gsrc,
                (__attribute__((address_space(3))) void*)(&sBb[grp * 512]),
                16, 0, 0);
        }
    };

    // ---- prologue ----
    float4 p0 = xrow[0], p1 = xrow[1];           // x(kt=0)
    __syncthreads();                             // s_tab visible (full drain, once)
    stage_b(&sB[0][0], 0);                       // 2 glds
    __builtin_amdgcn_sched_barrier(0);
    float4 xs0a = xrow[8], xs0b = xrow[9];       // x(kt=1), stays in flight
    __builtin_amdgcn_sched_barrier(0);
    stage_a(&sA[0][0], p0, p1, 0);
    __builtin_amdgcn_sched_barrier(0);
    asm volatile("s_waitcnt vmcnt(2) lgkmcnt(0)" ::: "memory");
    __builtin_amdgcn_sched_barrier(0);
    __builtin_amdgcn_s_barrier();                // buf0 staged; x(kt1) in flight

    for (int kt = 0; kt < 16; ++kt) {
        const int p = kt & 1;
        const int q = p ^ 1;
        const bool do_stage = (kt < 15);

        float4 xna = xs0a, xnb = xs0b;
        if (do_stage) {
            // oldest vmem this iter: 2 glds for sB[q]
            stage_b(&sB[q][0], kt + 1);
            __builtin_amdgcn_sched_barrier(0);
            // then exactly 2 x loads (kt+2, wrapped at tail -> uniform count)
            const int ktn = ((kt + 2) & 15) * 8;
            xna = xrow[ktn];
            xnb = xrow[ktn + 1];
            __builtin_amdgcn_sched_barrier(0);
            // spline + ds_write A for kt+1 (consumes x loaded last iter;
            // compiler waits vmcnt(4) -> this iter's 4 vmem stay in flight)
            stage_a(&sA[q][0], xs0a, xs0b, kt + 1);
        }

        // ---- compute on buf p: 16 MFMAs per wave ----
        const u16* sAc = &sA[p][0];
        const u16* sBc = &sB[p][0];
        bf16x8 afrag[2];
#pragma unroll
        for (int fm = 0; fm < 2; fm++) {
            int m_l = wave_m * 32 + fm * 16 + l15;
            int ci = (m_l << 2) | (quad ^ ((m_l >> 1) & 3));
            afrag[fm] = *reinterpret_cast<const bf16x8*>(&sAc[ci * 8]);
        }
        __builtin_amdgcn_s_setprio(1);
#pragma unroll
        for (int fn = 0; fn < 8; fn++) {
            int n_l = wave_n * 128 + fn * 16 + l15;
            int ci = (n_l << 2) | (quad ^ ((n_l >> 1) & 3));
            bf16x8 bfrag = *reinterpret_cast<const bf16x8*>(&sBc[ci * 8]);
#pragma unroll
            for (int fm = 0; fm < 2; fm++)
                acc[fm][fn] = __builtin_amdgcn_mfma_f32_16x16x32_bf16(
                    afrag[fm], bfrag, acc[fm][fn], 0, 0, 0);
        }
        __builtin_amdgcn_s_setprio(0);

        if (do_stage) {
            // counted wait: drains this iter's 2 glds (oldest) + all LDS ops;
            // the 2 x-prefetch loads stay in flight across the barrier.
            __builtin_amdgcn_sched_barrier(0);
            asm volatile("s_waitcnt vmcnt(2) lgkmcnt(0)" ::: "memory");
            __builtin_amdgcn_sched_barrier(0);
            __builtin_amdgcn_s_barrier();
        }
        xs0a = xna;
        xs0b = xnb;
    }

    // ---- epilogue: C/D layout col=lane&15, row=quad*4+j ----
#pragma unroll
    for (int fn = 0; fn < 8; fn++) {
        int o = n0 + wave_n * 128 + fn * 16 + l15;
        float bv = bias[o];
#pragma unroll
        for (int fm = 0; fm < 2; fm++) {
            int row = m0 + wave_m * 32 + fm * 16 + quad * 4;
            float* yp = y + (size_t)row * DIMN + o;
#pragma unroll
            for (int j = 0; j < 4; j++)
                yp[(size_t)j * DIMN] = acc[fm][fn][j] + bv;
        }
    }
}

extern "C" void kernel_launch(void* const* d_in, const int* in_sizes, int n_in,
                              void* d_out, int out_size, void* d_ws, size_t ws_size,
                              hipStream_t stream) {
    const float* x = (const float*)d_in[0];
    const float* bases = (const float*)d_in[1];
    const float* slopes = (const float*)d_in[2];
    const float* mix = (const float*)d_in[3];
    const float* bias = (const float*)d_in[4];
    float* y = (float*)d_out;

    u16* mixb = (u16*)d_ws;  // 512 KB bf16 mix

    hipLaunchKernelGGL(prep_kernel, dim3(256), dim3(256), 0, stream, mix, mixb);
    hipLaunchKernelGGL(kan_kernel, dim3(1024), dim3(512), 0, stream,
                       x, bases, slopes, mixb, bias, y);
}